// Round 8
// baseline (97.324 us; speedup 1.0000x reference)
//
#include <hip/hip_runtime.h>
#include <math.h>

#define N 8
#define C 256
#define L 512
#define K 100
#define NL (N * L)
#define EPSN 1e-8f

// ws layout: cn[NL*C] f32 (4 MB) | zq[NL*C] fp8-e4m3 (1 MB) | partials[1024] f32
//            | counter[1] u32

typedef float v2f __attribute__((ext_vector_type(2)));

__device__ __forceinline__ unsigned char f2fp8(float x) {
    return (unsigned char)(__builtin_amdgcn_cvt_pk_fp8_f32(x, x, 0, false) & 0xff);
}

// K1: transpose (N,C,L)->(NL,C) + fp32 normalize; c -> fp32 cn, z -> fp8 zq.
// 256 blocks: tile = 256 c's x 32 l's, full-128B-line global reads.
// Also zeroes the completion counter for K2's single-pass reduction.
__global__ __launch_bounds__(256) void prep_kernel(
    const float* __restrict__ z, const float* __restrict__ c,
    unsigned char* __restrict__ zq, float* __restrict__ cn,
    unsigned* __restrict__ counter)
{
    if (blockIdx.x == 0 && threadIdx.x == 0) *counter = 0u;

    __shared__ float tile[256 * 33];   // [c][l], pad 33: conflict-free
    __shared__ float red[256];
    __shared__ float linv[32];

    const int b    = blockIdx.x;
    const int is_c = b >= 128;
    const int bb   = b & 127;
    const int n    = bb >> 4;
    const int l0   = (bb & 15) << 5;     // 32 l's per block
    const int ld   = is_c ? (L + 1) : L;
    const float* src = (is_c ? c : z) + (size_t)n * C * ld + (is_c ? 1 : 0) + l0;

    const int t   = threadIdx.x;
    const int lcl = t & 31;              // local l (128B coalesced)
    const int cg  = t >> 5;              // c group

    float ss = 0.f;
    #pragma unroll
    for (int i = 0; i < 32; ++i) {
        const int cidx = i * 8 + cg;
        const float v = src[(size_t)cidx * ld + lcl];
        tile[cidx * 33 + lcl] = v;
        ss += v * v;
    }
    red[t] = ss;
    __syncthreads();
    if (t < 32) {
        float tot = 0.f;
        #pragma unroll
        for (int j = 0; j < 8; ++j) tot += red[j * 32 + t];
        linv[t] = 1.f / fmaxf(sqrtf(tot), EPSN);
    }
    __syncthreads();
    if (is_c) {
        float* dst = cn + (size_t)(n * L + l0) * C;
        #pragma unroll
        for (int j = 0; j < 32; ++j)
            dst[(size_t)j * C + t] = tile[t * 33 + j] * linv[j];   // coalesced
    } else {
        unsigned char* dst = zq + (size_t)(n * L + l0) * C;
        #pragma unroll
        for (int j = 0; j < 32; ++j)
            dst[(size_t)j * C + t] = f2fp8(tile[t * 33 + j] * linv[j]);
    }
}

// K2: one wave per row; four targets per gather wave-op (fp8 row = 256B,
// 16 lanes/target x 16B = 16 channels/lane). 128 padded targets in 2 batches
// of 64. Packed v2f accumulate (v_pk_fma_f32 against cvt_pk_f32_fp8 pairs).
// Phase 2: each lane owns one target, in-lane b128 partial sums, no shfl.
// Fixed-shift LSE (logit = 2*cos <= 2). Tail: single-pass last-block reduce.
__global__ __launch_bounds__(256, 4) void logits_kernel(
    const unsigned char* __restrict__ zq, const float* __restrict__ cn,
    const int* __restrict__ neg,
    const float* __restrict__ z, const float* __restrict__ c,
    float* __restrict__ partials, unsigned* __restrict__ counter,
    float* __restrict__ out)
{
    __shared__ float buf[4][2 * 16 * 68];   // 34.8 KB, double-buffered
    __shared__ float wterm[4];
    __shared__ int lastflag;
    __shared__ float red2[4];

    const int w = threadIdx.x >> 6, lane = threadIdx.x & 63;
    const int row = __builtin_amdgcn_readfirstlane((int)blockIdx.x * 4 + w);
    const int* __restrict__ negp = neg + (size_t)row * K;
    const int g = lane >> 4;             // target within quad
    const int k = lane & 15;             // 16-channel chunk

    const float* crow = cn + (size_t)row * C + k * 16;
    const float4 f0 = *(const float4*)(crow);
    const float4 f1 = *(const float4*)(crow + 4);
    const float4 f2 = *(const float4*)(crow + 8);
    const float4 f3 = *(const float4*)(crow + 12);
    const v2f ca0 = {f0.x, f0.y}, ca1 = {f0.z, f0.w};
    const v2f ca2 = {f1.x, f1.y}, ca3 = {f1.z, f1.w};
    const v2f ca4 = {f2.x, f2.y}, ca5 = {f2.z, f2.w};
    const v2f ca6 = {f3.x, f3.y}, ca7 = {f3.z, f3.w};

    float s_acc = 0.f, pos = 0.f;

    #pragma unroll 1
    for (int b = 0; b < 2; ++b) {
        float* __restrict__ pb = &buf[w][b * (16 * 68)];
        // ---- phase 1: 16 wave-ops cover 64 targets ----
        #pragma unroll 8
        for (int r = 0; r < 16; ++r) {
            const int t0 = b * 64 + 4 * r;
            const int i0 = (t0 == 0) ? row
                : ((t0 <= K) ? __builtin_amdgcn_readfirstlane(negp[t0 - 1]) : row);
            const int i1 = (t0 + 1 <= K) ? __builtin_amdgcn_readfirstlane(negp[t0]) : row;
            const int i2 = (t0 + 2 <= K) ? __builtin_amdgcn_readfirstlane(negp[t0 + 1]) : row;
            const int i3 = (t0 + 3 <= K) ? __builtin_amdgcn_readfirstlane(negp[t0 + 2]) : row;
            const int idx = (g == 0) ? i0 : (g == 1) ? i1 : (g == 2) ? i2 : i3;
            const uint4 zd = *(const uint4*)(zq + (size_t)idx * C + k * 16);
            v2f acc;
            acc  = ca0 * __builtin_amdgcn_cvt_pk_f32_fp8(zd.x, false);
            acc += ca1 * __builtin_amdgcn_cvt_pk_f32_fp8(zd.x, true);
            acc += ca2 * __builtin_amdgcn_cvt_pk_f32_fp8(zd.y, false);
            acc += ca3 * __builtin_amdgcn_cvt_pk_f32_fp8(zd.y, true);
            acc += ca4 * __builtin_amdgcn_cvt_pk_f32_fp8(zd.z, false);
            acc += ca5 * __builtin_amdgcn_cvt_pk_f32_fp8(zd.z, true);
            acc += ca6 * __builtin_amdgcn_cvt_pk_f32_fp8(zd.w, false);
            acc += ca7 * __builtin_amdgcn_cvt_pk_f32_fp8(zd.w, true);
            pb[r * 68 + g * 16 + k] = acc.x + acc.y;   // 2-way bank alias: free
        }
        // ---- phase 2: lane owns target t = b*64 + lane ----
        const int t = b * 64 + lane;
        const float* qp = pb + (lane >> 2) * 68 + (lane & 3) * 16;
        const float4 a0 = *(const float4*)(qp);
        const float4 a1 = *(const float4*)(qp + 4);
        const float4 a2 = *(const float4*)(qp + 8);
        const float4 a3 = *(const float4*)(qp + 12);
        const float dt = ((a0.x + a0.y) + (a0.z + a0.w))
                       + ((a1.x + a1.y) + (a1.z + a1.w))
                       + ((a2.x + a2.y) + (a2.z + a2.w))
                       + ((a3.x + a3.y) + (a3.z + a3.w));
        const float sim2 = dt * 2.0f;        // logit = 2*cos, max = 2
        if (t == 0) pos = sim2;              // lane 0, batch 0

        bool use = (t <= K);
        if (use && t >= 1 && sim2 > 1.9f) {  // exact-equal mask (rare path)
            const int idxv = negp[t - 1];
            const int nr = row >> 9, lr = row & 511;
            const int ni = idxv >> 9, li = idxv & 511;
            bool eq = true;
            for (int e = 0; e < C && eq; ++e)
                eq = (c[((size_t)nr * C + e) * (L + 1) + lr + 1]
                      == z[((size_t)ni * C + e) * L + li]);
            if (eq) use = false;             // masked -inf -> contributes 0
        }
        if (use) s_acc += __expf(sim2 - 2.0f);
    }

    #pragma unroll
    for (int m = 1; m < 64; m <<= 1) s_acc += __shfl_xor(s_acc, m, 64);
    if (lane == 0) wterm[w] = 2.0f + __logf(s_acc) - pos;
    __syncthreads();

    // ---- single-pass final reduction: last finishing block sums partials ----
    if (threadIdx.x == 0) {
        partials[blockIdx.x] = wterm[0] + wterm[1] + wterm[2] + wterm[3];
        __threadfence();                                  // release partial
        const unsigned old = atomicAdd(counter, 1u);      // device-scope
        lastflag = (old == (unsigned)(gridDim.x - 1));
    }
    __syncthreads();
    if (lastflag) {
        __threadfence();                                  // acquire others' partials
        const int t = threadIdx.x;
        float s = partials[t] + partials[t + 256] + partials[t + 512] + partials[t + 768];
        #pragma unroll
        for (int m = 1; m < 64; m <<= 1) s += __shfl_xor(s, m, 64);
        if ((t & 63) == 0) red2[t >> 6] = s;
        __syncthreads();
        if (t == 0) out[0] = (red2[0] + red2[1] + red2[2] + red2[3]) * (1.0f / NL);
    }
}

extern "C" void kernel_launch(void* const* d_in, const int* in_sizes, int n_in,
                              void* d_out, int out_size, void* d_ws, size_t ws_size,
                              hipStream_t stream) {
    const float* z = (const float*)d_in[0];
    const float* c = (const float*)d_in[1];
    const int* neg = (const int*)d_in[2];
    float* out = (float*)d_out;

    float* cn = (float*)d_ws;
    unsigned char* zq = (unsigned char*)(cn + (size_t)NL * C);
    float* partials = (float*)(zq + (size_t)NL * C);
    unsigned* counter = (unsigned*)(partials + 1024);

    prep_kernel<<<256, 256, 0, stream>>>(z, c, zq, cn, counter);
    logits_kernel<<<NL / 4, 256, 0, stream>>>(zq, cn, neg, z, c,
                                              partials, counter, out);
}

// Round 9
// 88.089 us; speedup vs baseline: 1.1048x; 1.1048x over previous
//
#include <hip/hip_runtime.h>
#include <math.h>

#define N 8
#define C 256
#define L 512
#define K 100
#define NL (N * L)
#define EPSN 1e-8f

// ws layout: cn[NL*C] f32 (4 MB) | zq[NL*C] fp8-e4m3 (1 MB) | partials[2048] f32

typedef float v2f __attribute__((ext_vector_type(2)));

__device__ __forceinline__ unsigned char f2fp8(float x) {
    return (unsigned char)(__builtin_amdgcn_cvt_pk_fp8_f32(x, x, 0, false) & 0xff);
}

// K1: transpose (N,C,L)->(NL,C) + fp32 normalize; c -> fp32 cn, z -> fp8 zq.
// 256 blocks: tile = 256 c's x 32 l's, full-128B-line global reads.
__global__ __launch_bounds__(256) void prep_kernel(
    const float* __restrict__ z, const float* __restrict__ c,
    unsigned char* __restrict__ zq, float* __restrict__ cn)
{
    __shared__ float tile[256 * 33];   // [c][l], pad 33: conflict-free
    __shared__ float red[256];
    __shared__ float linv[32];

    const int b    = blockIdx.x;
    const int is_c = b >= 128;
    const int bb   = b & 127;
    const int n    = bb >> 4;
    const int l0   = (bb & 15) << 5;     // 32 l's per block
    const int ld   = is_c ? (L + 1) : L;
    const float* src = (is_c ? c : z) + (size_t)n * C * ld + (is_c ? 1 : 0) + l0;

    const int t   = threadIdx.x;
    const int lcl = t & 31;              // local l (128B coalesced)
    const int cg  = t >> 5;              // c group

    float ss = 0.f;
    #pragma unroll
    for (int i = 0; i < 32; ++i) {
        const int cidx = i * 8 + cg;
        const float v = src[(size_t)cidx * ld + lcl];
        tile[cidx * 33 + lcl] = v;
        ss += v * v;
    }
    red[t] = ss;
    __syncthreads();
    if (t < 32) {
        float tot = 0.f;
        #pragma unroll
        for (int j = 0; j < 8; ++j) tot += red[j * 32 + t];
        linv[t] = 1.f / fmaxf(sqrtf(tot), EPSN);
    }
    __syncthreads();
    if (is_c) {
        float* dst = cn + (size_t)(n * L + l0) * C;
        #pragma unroll
        for (int j = 0; j < 32; ++j)
            dst[(size_t)j * C + t] = tile[t * 33 + j] * linv[j];   // coalesced
    } else {
        unsigned char* dst = zq + (size_t)(n * L + l0) * C;
        #pragma unroll
        for (int j = 0; j < 32; ++j)
            dst[(size_t)j * C + t] = f2fp8(tile[t * 33 + j] * linv[j]);
    }
}

// K2: 2 waves per row (64 targets each), 2 rows per block, grid 2048.
// Four targets per gather wave-op (fp8 row = 256B, 16 lanes/target x 16B).
// Packed v2f accumulate. Phase 2: lane owns one target, in-lane b128 sums,
// no shfl. Fixed-shift LSE (logit = 2*cos <= 2). partials -> reduce kernel.
__global__ __launch_bounds__(256, 8) void logits_kernel(
    const unsigned char* __restrict__ zq, const float* __restrict__ cn,
    const int* __restrict__ neg,
    const float* __restrict__ z, const float* __restrict__ c,
    float* __restrict__ partials)
{
    __shared__ float buf[4][16 * 68];   // 17.4 KB total -> 8 blocks/CU
    __shared__ float wacc[4];
    __shared__ float wpos[2];

    const int w = threadIdx.x >> 6, lane = threadIdx.x & 63;
    const int rl = w >> 1;               // row slot in block
    const int h  = w & 1;                // target half (0: 0-63, 1: 64-127)
    const int row = __builtin_amdgcn_readfirstlane((int)blockIdx.x * 2 + rl);
    const int* __restrict__ negp = neg + (size_t)row * K;
    const int g = lane >> 4;             // target within quad
    const int k = lane & 15;             // 16-channel chunk

    const float* crow = cn + (size_t)row * C + k * 16;
    const float4 f0 = *(const float4*)(crow);
    const float4 f1 = *(const float4*)(crow + 4);
    const float4 f2 = *(const float4*)(crow + 8);
    const float4 f3 = *(const float4*)(crow + 12);
    const v2f ca0 = {f0.x, f0.y}, ca1 = {f0.z, f0.w};
    const v2f ca2 = {f1.x, f1.y}, ca3 = {f1.z, f1.w};
    const v2f ca4 = {f2.x, f2.y}, ca5 = {f2.z, f2.w};
    const v2f ca6 = {f3.x, f3.y}, ca7 = {f3.z, f3.w};

    float* __restrict__ pb = &buf[w][0];

    // ---- phase 1: 16 wave-ops cover this wave's 64 targets ----
    #pragma unroll 8
    for (int r = 0; r < 16; ++r) {
        const int t0 = h * 64 + 4 * r;
        const int i0 = (t0 == 0) ? row
            : ((t0 <= K) ? __builtin_amdgcn_readfirstlane(negp[t0 - 1]) : row);
        const int i1 = (t0 + 1 <= K) ? __builtin_amdgcn_readfirstlane(negp[t0]) : row;
        const int i2 = (t0 + 2 <= K) ? __builtin_amdgcn_readfirstlane(negp[t0 + 1]) : row;
        const int i3 = (t0 + 3 <= K) ? __builtin_amdgcn_readfirstlane(negp[t0 + 2]) : row;
        const int idx = (g == 0) ? i0 : (g == 1) ? i1 : (g == 2) ? i2 : i3;
        const uint4 zd = *(const uint4*)(zq + (size_t)idx * C + k * 16);
        v2f acc;
        acc  = ca0 * __builtin_amdgcn_cvt_pk_f32_fp8(zd.x, false);
        acc += ca1 * __builtin_amdgcn_cvt_pk_f32_fp8(zd.x, true);
        acc += ca2 * __builtin_amdgcn_cvt_pk_f32_fp8(zd.y, false);
        acc += ca3 * __builtin_amdgcn_cvt_pk_f32_fp8(zd.y, true);
        acc += ca4 * __builtin_amdgcn_cvt_pk_f32_fp8(zd.z, false);
        acc += ca5 * __builtin_amdgcn_cvt_pk_f32_fp8(zd.z, true);
        acc += ca6 * __builtin_amdgcn_cvt_pk_f32_fp8(zd.w, false);
        acc += ca7 * __builtin_amdgcn_cvt_pk_f32_fp8(zd.w, true);
        pb[r * 68 + g * 16 + k] = acc.x + acc.y;   // 2-way bank alias: free
    }

    // ---- phase 2: lane owns target t = h*64 + lane ----
    const int t = h * 64 + lane;
    const float* qp = pb + (lane >> 2) * 68 + (lane & 3) * 16;
    const float4 a0 = *(const float4*)(qp);
    const float4 a1 = *(const float4*)(qp + 4);
    const float4 a2 = *(const float4*)(qp + 8);
    const float4 a3 = *(const float4*)(qp + 12);
    const float dt = ((a0.x + a0.y) + (a0.z + a0.w))
                   + ((a1.x + a1.y) + (a1.z + a1.w))
                   + ((a2.x + a2.y) + (a2.z + a2.w))
                   + ((a3.x + a3.y) + (a3.z + a3.w));
    const float sim2 = dt * 2.0f;        // logit = 2*cos, max = 2
    if (t == 0) wpos[rl] = sim2;

    bool use = (t <= K);
    if (use && t >= 1 && sim2 > 1.9f) {  // exact-equal mask (rare path)
        const int idxv = negp[t - 1];
        const int nr = row >> 9, lr = row & 511;
        const int ni = idxv >> 9, li = idxv & 511;
        bool eq = true;
        for (int e = 0; e < C && eq; ++e)
            eq = (c[((size_t)nr * C + e) * (L + 1) + lr + 1]
                  == z[((size_t)ni * C + e) * L + li]);
        if (eq) use = false;             // masked -inf -> contributes 0
    }
    float s_acc = use ? __expf(sim2 - 2.0f) : 0.f;

    #pragma unroll
    for (int m = 1; m < 64; m <<= 1) s_acc += __shfl_xor(s_acc, m, 64);
    if (lane == 0) wacc[w] = s_acc;
    __syncthreads();
    if (threadIdx.x == 0) {
        const float t0v = 2.0f + __logf(wacc[0] + wacc[1]) - wpos[0];
        const float t1v = 2.0f + __logf(wacc[2] + wacc[3]) - wpos[1];
        partials[blockIdx.x] = t0v + t1v;
    }
}

// K3: reduce 2048 block partials -> mean loss.
__global__ __launch_bounds__(256) void reduce_kernel(
    const float* __restrict__ p, float* __restrict__ out)
{
    __shared__ float red[4];
    const int t = threadIdx.x;
    float s = 0.f;
    #pragma unroll
    for (int kk = 0; kk < 8; ++kk) s += p[t + kk * 256];
    #pragma unroll
    for (int m = 1; m < 64; m <<= 1) s += __shfl_xor(s, m, 64);
    if ((t & 63) == 0) red[t >> 6] = s;
    __syncthreads();
    if (t == 0) out[0] = (red[0] + red[1] + red[2] + red[3]) * (1.0f / NL);
}

extern "C" void kernel_launch(void* const* d_in, const int* in_sizes, int n_in,
                              void* d_out, int out_size, void* d_ws, size_t ws_size,
                              hipStream_t stream) {
    const float* z = (const float*)d_in[0];
    const float* c = (const float*)d_in[1];
    const int* neg = (const int*)d_in[2];
    float* out = (float*)d_out;

    float* cn = (float*)d_ws;
    unsigned char* zq = (unsigned char*)(cn + (size_t)NL * C);
    float* partials = (float*)(zq + (size_t)NL * C);

    prep_kernel<<<256, 256, 0, stream>>>(z, c, zq, cn);
    logits_kernel<<<NL / 2, 256, 0, stream>>>(zq, cn, neg, z, c, partials);
    reduce_kernel<<<1, 256, 0, stream>>>(partials, out);
}

// Round 10
// 82.984 us; speedup vs baseline: 1.1728x; 1.0615x over previous
//
#include <hip/hip_runtime.h>
#include <math.h>

#define N 8
#define C 256
#define L 512
#define K 100
#define NL (N * L)
#define EPSN 1e-8f

// ws layout: cn[NL*C] f32 (4 MB) | zq[NL*C] fp8-e4m3 (1 MB) | partials[1024] f32

typedef float v2f __attribute__((ext_vector_type(2)));

__device__ __forceinline__ unsigned char f2fp8(float x) {
    return (unsigned char)(__builtin_amdgcn_cvt_pk_fp8_f32(x, x, 0, false) & 0xff);
}

// K1: transpose (N,C,L)->(NL,C) + fp32 normalize; c -> fp32 cn, z -> fp8 zq.
// 256 blocks: tile = 256 c's x 32 l's, full-128B-line global reads.
__global__ __launch_bounds__(256) void prep_kernel(
    const float* __restrict__ z, const float* __restrict__ c,
    unsigned char* __restrict__ zq, float* __restrict__ cn)
{
    __shared__ float tile[256 * 33];   // [c][l], pad 33: conflict-free
    __shared__ float red[256];
    __shared__ float linv[32];

    const int b    = blockIdx.x;
    const int is_c = b >= 128;
    const int bb   = b & 127;
    const int n    = bb >> 4;
    const int l0   = (bb & 15) << 5;     // 32 l's per block
    const int ld   = is_c ? (L + 1) : L;
    const float* src = (is_c ? c : z) + (size_t)n * C * ld + (is_c ? 1 : 0) + l0;

    const int t   = threadIdx.x;
    const int lcl = t & 31;              // local l (128B coalesced)
    const int cg  = t >> 5;              // c group

    float ss = 0.f;
    #pragma unroll
    for (int i = 0; i < 32; ++i) {
        const int cidx = i * 8 + cg;
        const float v = src[(size_t)cidx * ld + lcl];
        tile[cidx * 33 + lcl] = v;
        ss += v * v;
    }
    red[t] = ss;
    __syncthreads();
    if (t < 32) {
        float tot = 0.f;
        #pragma unroll
        for (int j = 0; j < 8; ++j) tot += red[j * 32 + t];
        linv[t] = 1.f / fmaxf(sqrtf(tot), EPSN);
    }
    __syncthreads();
    if (is_c) {
        float* dst = cn + (size_t)(n * L + l0) * C;
        #pragma unroll
        for (int j = 0; j < 32; ++j)
            dst[(size_t)j * C + t] = tile[t * 33 + j] * linv[j];   // coalesced
    } else {
        unsigned char* dst = zq + (size_t)(n * L + l0) * C;
        #pragma unroll
        for (int j = 0; j < 32; ++j)
            dst[(size_t)j * C + t] = f2fp8(tile[t * 33 + j] * linv[j]);
    }
}

// K2: one wave per row; four targets per gather wave-op (fp8 row = 256B,
// 16 lanes/target x 16B = 16 channels/lane). 128 padded targets in 2 batches
// of 64. Packed v2f accumulate (v_pk_fma_f32 on cvt_pk_f32_fp8 pairs).
// Phase 2: each lane owns one target, in-lane b128 sums, no shfl.
// Fixed-shift LSE (logit = 2*cos <= 2). No global atomics.
__global__ __launch_bounds__(256, 4) void logits_kernel(
    const unsigned char* __restrict__ zq, const float* __restrict__ cn,
    const int* __restrict__ neg,
    const float* __restrict__ z, const float* __restrict__ c,
    float* __restrict__ partials)
{
    __shared__ float buf[4][2 * 16 * 68];   // 34.8 KB, double-buffered
    __shared__ float wterm[4];

    const int w = threadIdx.x >> 6, lane = threadIdx.x & 63;
    const int row = __builtin_amdgcn_readfirstlane((int)blockIdx.x * 4 + w);
    const int* __restrict__ negp = neg + (size_t)row * K;
    const int g = lane >> 4;             // target within quad
    const int k = lane & 15;             // 16-channel chunk

    const float* crow = cn + (size_t)row * C + k * 16;
    const float4 f0 = *(const float4*)(crow);
    const float4 f1 = *(const float4*)(crow + 4);
    const float4 f2 = *(const float4*)(crow + 8);
    const float4 f3 = *(const float4*)(crow + 12);
    const v2f ca0 = {f0.x, f0.y}, ca1 = {f0.z, f0.w};
    const v2f ca2 = {f1.x, f1.y}, ca3 = {f1.z, f1.w};
    const v2f ca4 = {f2.x, f2.y}, ca5 = {f2.z, f2.w};
    const v2f ca6 = {f3.x, f3.y}, ca7 = {f3.z, f3.w};

    float s_acc = 0.f, pos = 0.f;

    #pragma unroll 1
    for (int b = 0; b < 2; ++b) {
        float* __restrict__ pb = &buf[w][b * (16 * 68)];
        // ---- phase 1: 16 wave-ops cover 64 targets ----
        #pragma unroll 8
        for (int r = 0; r < 16; ++r) {
            const int t0 = b * 64 + 4 * r;
            const int i0 = (t0 == 0) ? row
                : ((t0 <= K) ? __builtin_amdgcn_readfirstlane(negp[t0 - 1]) : row);
            const int i1 = (t0 + 1 <= K) ? __builtin_amdgcn_readfirstlane(negp[t0]) : row;
            const int i2 = (t0 + 2 <= K) ? __builtin_amdgcn_readfirstlane(negp[t0 + 1]) : row;
            const int i3 = (t0 + 3 <= K) ? __builtin_amdgcn_readfirstlane(negp[t0 + 2]) : row;
            const int idx = (g == 0) ? i0 : (g == 1) ? i1 : (g == 2) ? i2 : i3;
            const uint4 zd = *(const uint4*)(zq + (size_t)idx * C + k * 16);
            v2f acc;
            acc  = ca0 * __builtin_amdgcn_cvt_pk_f32_fp8(zd.x, false);
            acc += ca1 * __builtin_amdgcn_cvt_pk_f32_fp8(zd.x, true);
            acc += ca2 * __builtin_amdgcn_cvt_pk_f32_fp8(zd.y, false);
            acc += ca3 * __builtin_amdgcn_cvt_pk_f32_fp8(zd.y, true);
            acc += ca4 * __builtin_amdgcn_cvt_pk_f32_fp8(zd.z, false);
            acc += ca5 * __builtin_amdgcn_cvt_pk_f32_fp8(zd.z, true);
            acc += ca6 * __builtin_amdgcn_cvt_pk_f32_fp8(zd.w, false);
            acc += ca7 * __builtin_amdgcn_cvt_pk_f32_fp8(zd.w, true);
            pb[r * 68 + g * 16 + k] = acc.x + acc.y;   // 2-way bank alias: free
        }
        // ---- phase 2: lane owns target t = b*64 + lane ----
        const int t = b * 64 + lane;
        const float* qp = pb + (lane >> 2) * 68 + (lane & 3) * 16;
        const float4 a0 = *(const float4*)(qp);
        const float4 a1 = *(const float4*)(qp + 4);
        const float4 a2 = *(const float4*)(qp + 8);
        const float4 a3 = *(const float4*)(qp + 12);
        const float dt = ((a0.x + a0.y) + (a0.z + a0.w))
                       + ((a1.x + a1.y) + (a1.z + a1.w))
                       + ((a2.x + a2.y) + (a2.z + a2.w))
                       + ((a3.x + a3.y) + (a3.z + a3.w));
        const float sim2 = dt * 2.0f;        // logit = 2*cos, max = 2
        if (t == 0) pos = sim2;              // lane 0, batch 0

        bool use = (t <= K);
        if (use && t >= 1 && sim2 > 1.9f) {  // exact-equal mask (rare path)
            const int idxv = negp[t - 1];
            const int nr = row >> 9, lr = row & 511;
            const int ni = idxv >> 9, li = idxv & 511;
            bool eq = true;
            for (int e = 0; e < C && eq; ++e)
                eq = (c[((size_t)nr * C + e) * (L + 1) + lr + 1]
                      == z[((size_t)ni * C + e) * L + li]);
            if (eq) use = false;             // masked -inf -> contributes 0
        }
        if (use) s_acc += __expf(sim2 - 2.0f);
    }

    #pragma unroll
    for (int m = 1; m < 64; m <<= 1) s_acc += __shfl_xor(s_acc, m, 64);
    if (lane == 0) wterm[w] = 2.0f + __logf(s_acc) - pos;
    __syncthreads();
    if (threadIdx.x == 0)
        partials[blockIdx.x] = wterm[0] + wterm[1] + wterm[2] + wterm[3];
}

// K3: reduce 1024 block partials -> mean loss.
__global__ __launch_bounds__(256) void reduce_kernel(
    const float* __restrict__ p, float* __restrict__ out)
{
    __shared__ float red[4];
    const int t = threadIdx.x;
    float s = p[t] + p[t + 256] + p[t + 512] + p[t + 768];
    #pragma unroll
    for (int m = 1; m < 64; m <<= 1) s += __shfl_xor(s, m, 64);
    if ((t & 63) == 0) red[t >> 6] = s;
    __syncthreads();
    if (t == 0) out[0] = (red[0] + red[1] + red[2] + red[3]) * (1.0f / NL);
}

extern "C" void kernel_launch(void* const* d_in, const int* in_sizes, int n_in,
                              void* d_out, int out_size, void* d_ws, size_t ws_size,
                              hipStream_t stream) {
    const float* z = (const float*)d_in[0];
    const float* c = (const float*)d_in[1];
    const int* neg = (const int*)d_in[2];
    float* out = (float*)d_out;

    float* cn = (float*)d_ws;
    unsigned char* zq = (unsigned char*)(cn + (size_t)NL * C);
    float* partials = (float*)(zq + (size_t)NL * C);

    prep_kernel<<<256, 256, 0, stream>>>(z, c, zq, cn);
    logits_kernel<<<NL / 4, 256, 0, stream>>>(zq, cn, neg, z, c, partials);
    reduce_kernel<<<1, 256, 0, stream>>>(partials, out);
}